// Round 3
// baseline (715.893 us; speedup 1.0000x reference)
//
#include <hip/hip_runtime.h>

#define BB 32
#define SS 4096
#define HH 1024
#define BS (BB * SS)
#define RPW 16                  // rows per wave
#define WPB (SS / RPW)          // 256 waves per batch
#define NBLOCKS (BB * WPB / 4)  // 2048 blocks of 4 waves

// Order-preserving float -> uint key (unsigned compare == float compare)
__device__ __forceinline__ unsigned fkey(float f) {
    unsigned u = __float_as_uint(f);
    return (u & 0x80000000u) ? ~u : (u | 0x80000000u);
}
__device__ __forceinline__ float funkey(unsigned k) {
    unsigned u = (k & 0x80000000u) ? (k ^ 0x80000000u) : ~k;
    return __uint_as_float(u);
}
__device__ __forceinline__ float dot4(float4 a, float4 w) {
    return a.x * w.x + a.y * w.y + a.z * w.z + a.w * w.w;
}

// Each wave: 16 consecutive rows. Stream loop has ONLY independent loads +
// FMAs (16 rows x 4 H-quarters); all reductions/stores/mask once at the end.
__global__ __launch_bounds__(256) void k_proj(
    const float* __restrict__ x, const int* __restrict__ mask,
    const float* __restrict__ W, const float* __restrict__ bvec,
    float* __restrict__ h, unsigned* __restrict__ mm)
{
    const int lane  = threadIdx.x & 63;
    const int gw    = blockIdx.x * 4 + (threadIdx.x >> 6);
    const int batch = gw >> 8;                       // gw / WPB
    const int rowStart = (batch << 12) + (gw & 255) * RPW;  // 16 consecutive rows

    const float4* Wv = (const float4*)W;
    const float4 w0 = Wv[lane], w1 = Wv[64 + lane],
                 w2 = Wv[128 + lane], w3 = Wv[192 + lane];

    float acc[RPW];
#pragma unroll
    for (int k = 0; k < RPW; ++k) acc[k] = 0.0f;

    // float4 pointer to this wave's first row, offset by lane
    const float4* xr = (const float4*)x + (size_t)rowStart * (HH / 4) + lane;

#pragma unroll
    for (int j = 0; j < 4; ++j) {                    // H-quarter (256 floats)
        const float4 wj = (j == 0) ? w0 : (j == 1) ? w1 : (j == 2) ? w2 : w3;
        float4 v[RPW];
#pragma unroll
        for (int k = 0; k < RPW; ++k)                // 16 independent 1KB loads
            v[k] = xr[k * (HH / 4) + j * 64];
#pragma unroll
        for (int k = 0; k < RPW; ++k)
            acc[k] += dot4(v[k], wj);
    }

    // 16 butterfly reductions; row k's total selected into lane k (static sel)
    float hsel = 0.0f;
#pragma unroll
    for (int k = 0; k < RPW; ++k) {
        float s = acc[k];
#pragma unroll
        for (int off = 32; off >= 1; off >>= 1)
            s += __shfl_xor(s, off, 64);
        if (lane == k) hsel = s;
    }

    const float hv = hsel + bvec[0];
    unsigned kmin = 0xFFFFFFFFu, kneg = 0xFFFFFFFFu;  // max tracked as min(-h)
    if (lane < RPW) {
        h[rowStart + lane] = hv;                      // one coalesced 64B store
        if (mask[rowStart + lane] != 0) {             // one coalesced 64B load
            kmin = fkey(hv);
            kneg = fkey(-hv);
        }
    }
#pragma unroll
    for (int off = 32; off >= 1; off >>= 1) {
        kmin = min(kmin, (unsigned)__shfl_xor((int)kmin, off, 64));
        kneg = min(kneg, (unsigned)__shfl_xor((int)kneg, off, 64));
    }
    if (lane == 0) {
        atomicMin(&mm[batch], kmin);       // device-scope: XCD-safe
        atomicMin(&mm[BB + batch], kneg);
    }
}

// out = mask ? (h - hmin)/(hmax - hmin) : 0   (mean/std cancel algebraically)
__global__ __launch_bounds__(256) void k_final(
    const float4* __restrict__ h4, const int4* __restrict__ mask4,
    const unsigned* __restrict__ mm, float4* __restrict__ out4)
{
    const int i = blockIdx.x * 256 + threadIdx.x;    // float4 index
    if (i >= BS / 4) return;
    const int batch = i >> 10;                       // (i*4) >> 12
    const float hmin =  funkey(mm[batch]);
    const float hmax = -funkey(mm[BB + batch]);
    const float inv  = 1.0f / (hmax - hmin);
    const float4 hv = h4[i];
    const int4  mv = mask4[i];
    float4 o;
    o.x = mv.x ? (hv.x - hmin) * inv : 0.0f;
    o.y = mv.y ? (hv.y - hmin) * inv : 0.0f;
    o.z = mv.z ? (hv.z - hmin) * inv : 0.0f;
    o.w = mv.w ? (hv.w - hmin) * inv : 0.0f;
    out4[i] = o;
}

extern "C" void kernel_launch(void* const* d_in, const int* in_sizes, int n_in,
                              void* d_out, int out_size, void* d_ws, size_t ws_size,
                              hipStream_t stream) {
    const float* x    = (const float*)d_in[0];
    const int*   mask = (const int*)d_in[1];
    const float* W    = (const float*)d_in[2];
    const float* bv   = (const float*)d_in[3];

    float*    h  = (float*)d_ws;                                   // BS floats
    unsigned* mm = (unsigned*)((char*)d_ws + (size_t)BS * 4);      // 2*BB uints

    // Both min and (negated) max slots init to 0xFFFFFFFF — single memset.
    hipMemsetAsync(mm, 0xFF, 2 * BB * sizeof(unsigned), stream);

    k_proj<<<NBLOCKS, 256, 0, stream>>>(x, mask, W, bv, h, mm);
    k_final<<<BS / 4 / 256, 256, 0, stream>>>((const float4*)h, (const int4*)mask,
                                              mm, (float4*)d_out);
}